// Round 7
// baseline (471.453 us; speedup 1.0000x reference)
//
#include <hip/hip_runtime.h>
#include <stdint.h>

// UnarySqrt scan, T=64 steps, N=2^20 channels, exact {0,1} floats.
//   p = x*(1-tr); out = tr + p; tr' = p
//
// Why hand-rolled asm pipeline: one time-row is N*4B = 4 MB = 16 KB/CU, so a
// depth-1 (compiler-scheduled) loop can never have more than ~16 KB/CU in
// flight -> ~2.4 TB/s latency-bound ceiling, which R1/R3/R5 all hit exactly.
// We need multiple rows in flight. The compiler collapses C-level rotating
// buffers (R5: VGPR=32), so all hot-loop VMEM is volatile asm with exact
// hand-placed vmcnt waits.
//
// Correctness vs R6 (which stored garbage): the HW reads store-data VGPRs
// *after* issue, so store-source registers must not be recycled until the
// store retires. Here obuf[t&3]'s old value (data of S(t-4)) is tied "+v"
// into step t's wait, whose vmcnt(6) guarantees S(t-4) completion before the
// register is redefined. Loads use voff(VGPR, never redefined) + SGPR base
// (latched at issue; standard compiler pattern). All VMEM ops are volatile
// asm -> program order preserved -> wait constants are exact:
//   issue stream: L0 L1 L2 L3 | [w L4 S0] [w L5 S1] ... [w L63 S59] | [w S60]..[w S63]
//   step t needs L(t) and S(t-4) done; ops issued after S(t-4) = 6 (steady).
//   Ramp-in: 3,4,5; steady 6; ramp-out 5,4,3.
// Steady in-flight: <=7 ops x 1KB/wave; 16 waves/CU -> ~112 KB/CU in flight.

typedef float v4f __attribute__((ext_vector_type(4)));

#define GLOADS(dst, voff, sb) \
    asm volatile("global_load_dwordx4 %0, %1, %2" \
                 : "=v"(dst) : "v"(voff), "s"(sb) : "memory")

#define GSTORES(val, voff, sb) \
    asm volatile("global_store_dwordx4 %0, %1, %2 nt" \
                 :: "v"(voff), "v"(val), "s"(sb) : "memory")

#define SWAIT2_(n, a, b) \
    asm volatile("s_waitcnt vmcnt(" #n ")" : "+v"(a), "+v"(b) :: "memory")
#define SWAIT2(n, a, b) SWAIT2_(n, a, b)

#define STEP(t, n) do { \
    SWAIT2(n, buf[(t) & 3], obuf[(t) & 3]); \
    v4f x = buf[(t) & 3]; \
    if ((t) + 4 < 64) { GLOADS(buf[(t) & 3], voff, inext); inext += rowb; } \
    v4f p = x * (1.0f - tr); \
    obuf[(t) & 3] = tr + p; \
    tr = p; \
    GSTORES(obuf[(t) & 3], voff, onext); onext += rowb; \
} while (0)

__global__ __launch_bounds__(256) void UnarySqrt_kernel(
    const float* __restrict__ in,      // [64, N]
    const float* __restrict__ trace0,  // [N]
    float* __restrict__ out,           // [64, N]
    int stride4)                        // N/4
{
    int idx = blockIdx.x * blockDim.x + threadIdx.x;
    if (idx >= stride4) return;

    v4f tr = ((const v4f*)trace0)[idx];
    // Force the compiler to drain its own (tracked) trace0 load HERE, before
    // our untracked pipeline loads start sharing the vmcnt counter.
    asm volatile("" : "+v"(tr));

    uint32_t voff = (uint32_t)idx * 16u;        // per-lane byte offset, never redefined
    uint64_t rowb = (uint64_t)stride4 * 16u;    // row stride in bytes
    uint64_t inext = (uint64_t)(uintptr_t)in + 4u * rowb;  // next row to load
    uint64_t onext = (uint64_t)(uintptr_t)out;             // next row to store

    v4f buf[4], obuf[4];
    v4f z = {0.f, 0.f, 0.f, 0.f};
    obuf[0] = z; obuf[1] = z; obuf[2] = z; obuf[3] = z;

    {   // prologue: rows 0..3 in flight
        uint64_t ip = (uint64_t)(uintptr_t)in;
        GLOADS(buf[0], voff, ip);  ip += rowb;
        GLOADS(buf[1], voff, ip);  ip += rowb;
        GLOADS(buf[2], voff, ip);  ip += rowb;
        GLOADS(buf[3], voff, ip);
    }

    STEP( 0,3); STEP( 1,4); STEP( 2,5); STEP( 3,6);
    STEP( 4,6); STEP( 5,6); STEP( 6,6); STEP( 7,6);
    STEP( 8,6); STEP( 9,6); STEP(10,6); STEP(11,6);
    STEP(12,6); STEP(13,6); STEP(14,6); STEP(15,6);
    STEP(16,6); STEP(17,6); STEP(18,6); STEP(19,6);
    STEP(20,6); STEP(21,6); STEP(22,6); STEP(23,6);
    STEP(24,6); STEP(25,6); STEP(26,6); STEP(27,6);
    STEP(28,6); STEP(29,6); STEP(30,6); STEP(31,6);
    STEP(32,6); STEP(33,6); STEP(34,6); STEP(35,6);
    STEP(36,6); STEP(37,6); STEP(38,6); STEP(39,6);
    STEP(40,6); STEP(41,6); STEP(42,6); STEP(43,6);
    STEP(44,6); STEP(45,6); STEP(46,6); STEP(47,6);
    STEP(48,6); STEP(49,6); STEP(50,6); STEP(51,6);
    STEP(52,6); STEP(53,6); STEP(54,6); STEP(55,6);
    STEP(56,6); STEP(57,6); STEP(58,6); STEP(59,6);
    STEP(60,6); STEP(61,5); STEP(62,4); STEP(63,3);

    asm volatile("s_waitcnt vmcnt(0)" ::: "memory");
}

// Generic fallback (correct for any T, N%4==0) in case the shape ever differs.
__global__ __launch_bounds__(256) void UnarySqrt_generic(
    const v4f* __restrict__ in, const v4f* __restrict__ trace0,
    v4f* __restrict__ out, int stride, int T)
{
    int idx = blockIdx.x * blockDim.x + threadIdx.x;
    if (idx >= stride) return;
    v4f tr = trace0[idx];
    for (int t = 0; t < T; ++t) {
        v4f x = in[(size_t)t * stride + idx];
        v4f p = x * (1.0f - tr);
        out[(size_t)t * stride + idx] = tr + p;
        tr = p;
    }
}

extern "C" void kernel_launch(void* const* d_in, const int* in_sizes, int n_in,
                              void* d_out, int out_size, void* d_ws, size_t ws_size,
                              hipStream_t stream) {
    const float* bits   = (const float*)d_in[0];  // [T, N]
    const float* trace0 = (const float*)d_in[1];  // [N]

    int N = in_sizes[1];
    int T = in_sizes[0] / N;
    int stride4 = N / 4;

    int block = 256;
    int grid = (stride4 + block - 1) / block;

    if (T == 64 && (N % 1024) == 0) {
        UnarySqrt_kernel<<<grid, block, 0, stream>>>(bits, trace0, (float*)d_out, stride4);
    } else {
        UnarySqrt_generic<<<grid, block, 0, stream>>>(
            (const v4f*)bits, (const v4f*)trace0, (v4f*)d_out, stride4, T);
    }
}

// Round 8
// 448.954 us; speedup vs baseline: 1.0501x; 1.0501x over previous
//
#include <hip/hip_runtime.h>
#include <stdint.h>

// UnarySqrt scan, T=64 steps, N=2^20 channels, exact {0,1} floats.
//   per step: p = x*(1-tr); out = tr + p; tr' = p
//
// R1/R3/R5/R7 all plateaued at ~2.2 TB/s: every variant had a per-time-step
// load->compute->store chain, and vmcnt retires IN ORDER across loads and
// stores, so each step's load-wait also waited on congested store acks ->
// effective pipeline depth ~1 no matter what the source said.
//
// This version removes the serial chain from the memory path. The recurrence
// is a 1-bit state machine, so 8 steps have a transfer function captured by
// two bits per channel: F(0), F(1). Block = 512 threads = 8 chunks x 64 lanes:
//   1. each thread loads its chunk's 8 rows (8 independent 16B loads,
//      copy-style MLP, no stores interleaved)
//   2. simulate chunk from tr=0 and tr=1  -> (F(0), F(1)) per channel
//   3. LDS exchange + prefix fold (<=7 wave-uniform iterations) resolves the
//      actual incoming trace for each chunk
//   4. recompute outputs with the real trace, 8 independent NT stores
// All selects are exact on {0,1} floats: sel(s,a,b) = a + s*(b-a).

typedef float v4f __attribute__((ext_vector_type(4)));

#define CHUNKS 8
#define CSTEPS 8  // 64 / CHUNKS

__global__ __launch_bounds__(512) void UnarySqrt_kernel(
    const v4f* __restrict__ in,      // [64, stride]
    const v4f* __restrict__ trace0,  // [stride]
    v4f* __restrict__ out,           // [64, stride]
    int stride)                       // N/4, divisible by 64 (checked on host)
{
    __shared__ v4f lds0[CHUNKS][64];
    __shared__ v4f lds1[CHUNKS][64];

    const int tid   = threadIdx.x;
    const int lane  = tid & 63;
    const int chunk = tid >> 6;                     // wave-uniform
    const size_t g  = (size_t)blockIdx.x * 64 + lane;  // v4f channel group

    // 1. Load 8 rows, fully independent -> 8 loads in flight per thread.
    v4f buf[CSTEPS];
    #pragma unroll
    for (int j = 0; j < CSTEPS; ++j) {
        buf[j] = in[(size_t)(chunk * CSTEPS + j) * (size_t)stride + g];
    }

    // 2. Chunk transfer function: simulate from tr=0 and tr=1.
    v4f tr0 = {0.f, 0.f, 0.f, 0.f};
    v4f tr1 = {1.f, 1.f, 1.f, 1.f};
    #pragma unroll
    for (int j = 0; j < CSTEPS; ++j) {
        tr0 = buf[j] * (1.0f - tr0);
        tr1 = buf[j] * (1.0f - tr1);
    }
    lds0[chunk][lane] = tr0;
    lds1[chunk][lane] = tr1;
    __syncthreads();

    // 3. Resolve incoming trace for this chunk: fold chunks 0..chunk-1
    //    starting from trace0. Loop count is wave-uniform (no divergence).
    v4f s = trace0[g];
    for (int k = 0; k < chunk; ++k) {
        v4f a = lds0[k][lane];
        v4f b = lds1[k][lane];
        s = a + s * (b - a);  // s ? b : a, exact on {0,1}
    }

    // 4. Final pass with the real trace; 8 independent streaming stores.
    v4f tr = s;
    #pragma unroll
    for (int j = 0; j < CSTEPS; ++j) {
        v4f p = buf[j] * (1.0f - tr);
        v4f o = tr + p;
        __builtin_nontemporal_store(
            o, &out[(size_t)(chunk * CSTEPS + j) * (size_t)stride + g]);
        tr = p;
    }
}

// Generic fallback (correct for any T, N%4==0).
__global__ __launch_bounds__(256) void UnarySqrt_generic(
    const v4f* __restrict__ in, const v4f* __restrict__ trace0,
    v4f* __restrict__ out, int stride, int T)
{
    int idx = blockIdx.x * blockDim.x + threadIdx.x;
    if (idx >= stride) return;
    v4f tr = trace0[idx];
    for (int t = 0; t < T; ++t) {
        v4f x = in[(size_t)t * stride + idx];
        v4f p = x * (1.0f - tr);
        out[(size_t)t * stride + idx] = tr + p;
        tr = p;
    }
}

extern "C" void kernel_launch(void* const* d_in, const int* in_sizes, int n_in,
                              void* d_out, int out_size, void* d_ws, size_t ws_size,
                              hipStream_t stream) {
    const float* bits   = (const float*)d_in[0];  // [T, N]
    const float* trace0 = (const float*)d_in[1];  // [N]

    int N = in_sizes[1];
    int T = in_sizes[0] / N;
    int stride = N / 4;

    if (T == 64 && (N % 256) == 0) {
        // block: 8 chunks x 64 lanes; each block covers 64 v4f channel groups.
        int grid = stride / 64;
        UnarySqrt_kernel<<<grid, 512, 0, stream>>>(
            (const v4f*)bits, (const v4f*)trace0, (v4f*)d_out, stride);
    } else {
        int block = 256;
        int grid = (stride + block - 1) / block;
        UnarySqrt_generic<<<grid, block, 0, stream>>>(
            (const v4f*)bits, (const v4f*)trace0, (v4f*)d_out, stride, T);
    }
}